// Round 3
// baseline (71.419 us; speedup 1.0000x reference)
//
#include <hip/hip_runtime.h>

// CenterLoss: loss = (1/B) * sum_b clip(||x_b - c_{l_b}||^2, 1e-12, 1e12)
//             + (C-1)*1e-12   (reference clamps the B*(C-1) masked zeros up
//             to 1e-12 before summing; exact, though far below tolerance)
//
// x: [B=8192, D=256] f32, labels: [B] int, centers: [C=10000, D=256] f32.
//
// R3 design: single fused kernel + 4-byte memset of d_out.
//   256 blocks x 1024 threads = 4096 waves, 2 samples per wave (independent
//   label->gather chains for ILP), 32 waves/CU. Per-block LDS reduce of the
//   16 wave partials, then ONE fp32 atomicAdd(out) per block (256 atomics,
//   same address ~ <1us, hidden under kernel spread). d_out is zeroed by
//   hipMemsetAsync (graph-capture safe; no dependence on anything, so it
//   overlaps the harness restore tail). Non-deterministic fp sum order:
//   jitter ~1e-4 vs tolerance 10.24.

#define NBLOCKS 256
#define TPB 1024
#define WPB (TPB / 64)           // 16 waves/block
// samples: NBLOCKS * WPB * 2 == 8192 == B

__global__ __launch_bounds__(TPB) void centerloss_fused(
    const float* __restrict__ x,
    const int* __restrict__ labels,
    const float* __restrict__ centers,
    float* __restrict__ out,
    int B, int C)
{
    const int lane   = threadIdx.x & 63;
    const int wlocal = threadIdx.x >> 6;
    const int w      = blockIdx.x * WPB + wlocal;     // global wave id
    const int b0     = w * 2;
    const int b1     = b0 + 1;

    // two independent label->gather chains per wave (ILP)
    const int l0 = labels[b0];
    const int l1 = labels[b1];
    const float4 xv0 = ((const float4*)(x       + (size_t)b0 * 256))[lane];
    const float4 xv1 = ((const float4*)(x       + (size_t)b1 * 256))[lane];
    const float4 cv0 = ((const float4*)(centers + (size_t)l0 * 256))[lane];
    const float4 cv1 = ((const float4*)(centers + (size_t)l1 * 256))[lane];

    // per-lane ||x||^2 + ||c||^2 - 2<x,c> = ||x-c||^2 contribution
    float d0x = xv0.x - cv0.x, d0y = xv0.y - cv0.y,
          d0z = xv0.z - cv0.z, d0w = xv0.w - cv0.w;
    float d1x = xv1.x - cv1.x, d1y = xv1.y - cv1.y,
          d1z = xv1.z - cv1.z, d1w = xv1.w - cv1.w;
    float v0 = d0x * d0x + d0y * d0y + d0z * d0z + d0w * d0w;
    float v1 = d1x * d1x + d1y * d1y + d1z * d1z + d1w * d1w;

    // wave-level sums (64 lanes), two chains interleaved
    #pragma unroll
    for (int off = 32; off > 0; off >>= 1) {
        v0 += __shfl_down(v0, off, 64);
        v1 += __shfl_down(v1, off, 64);
    }

    __shared__ float s[WPB];
    if (lane == 0)
        s[wlocal] = fminf(fmaxf(v0, 1e-12f), 1e12f)
                  + fminf(fmaxf(v1, 1e-12f), 1e12f);
    __syncthreads();

    if (threadIdx.x == 0) {
        float t = 0.0f;
        #pragma unroll
        for (int i = 0; i < WPB; ++i) t += s[i];
        float contrib = t * (1.0f / 8192.0f);
        if (blockIdx.x == 0)
            contrib += (float)((double)(C - 1) * 1e-12);  // clamped-zeros term
        atomicAdd(out, contrib);
    }
}

extern "C" void kernel_launch(void* const* d_in, const int* in_sizes, int n_in,
                              void* d_out, int out_size, void* d_ws, size_t ws_size,
                              hipStream_t stream)
{
    const float* x       = (const float*)d_in[0];
    const int*   labels  = (const int*)d_in[1];
    const float* centers = (const float*)d_in[2];

    const int B = in_sizes[1];                 // 8192
    const int D = in_sizes[0] / B;             // 256 (layout assumed)
    const int C = in_sizes[2] / D;             // 10000

    float* out = (float*)d_out;

    hipMemsetAsync(out, 0, sizeof(float), stream);   // d_out poisoned 0xAA
    centerloss_fused<<<NBLOCKS, TPB, 0, stream>>>(x, labels, centers, out, B, C);
}